// Round 12
// baseline (391.704 us; speedup 1.0000x reference)
//
#include <hip/hip_runtime.h>

// ---------------------------------------------------------------------------
// PointNet2-AT inference pipeline, bf16 MFMA GEMMs + fp32 epilogues.
// B=16, N=4096 -> M = 65536 rows everywhere.
// R5 GEMM config (proven): 128x128 tile, BK=64, XOR bank-deswizzle,
//   global_load_lds 16B, XCD-aware grid swizzle, 0 bank conflicts.
// R8: SA1 megafusion. R11: GEMM-body isolation (clone per variant). 359.6us.
// R12: S3 -> gemm_bk32 (BK=32, 16KB LDS, m97-prior: finer barrier pairs;
//   XOR key for 64B row stride: slot = q ^ ((lm>>1)&3), 0-conflict by the
//   same bank math as R5). S2 keeps the proven BK=64 body. Pool -> uint4
//   16B loads, 8 cols/thread, 2 n-halves combined in LDS.
// ---------------------------------------------------------------------------

#define M_ROWS 65536
#define MB ((size_t)1 << 20)

typedef __bf16 bf16x8 __attribute__((ext_vector_type(8)));
typedef float floatx4 __attribute__((ext_vector_type(4)));

__device__ __forceinline__ float b2f(ushort u) {
    unsigned int x = ((unsigned int)u) << 16;
    float f;
    __builtin_memcpy(&f, &x, 4);
    return f;
}
__device__ __forceinline__ ushort f2bf(float f) {
    unsigned int x;
    __builtin_memcpy(&x, &f, 4);
    unsigned int r = x + 0x7fffu + ((x >> 16) & 1u);  // RNE
    return (ushort)(r >> 16);
}
__device__ __forceinline__ float lo16(unsigned u) { return b2f((ushort)(u & 0xffffu)); }
__device__ __forceinline__ float hi16(unsigned u) { return b2f((ushort)(u >> 16)); }

// async global->LDS, 16B per lane; LDS dest = wave-uniform base + lane*16
__device__ __forceinline__ void gl_lds16(const ushort* g, ushort* l) {
    __builtin_amdgcn_global_load_lds(
        (const __attribute__((address_space(1))) unsigned int*)g,
        (__attribute__((address_space(3))) unsigned int*)l, 16, 0, 0);
}

// ---------------------------------------------------------------------------
// Prep2: LDS-tiled transpose of 5 bf16 GEMM weights (w==2 = sa3_w1 rows
// 3..258 only -> WtS1 [256][256]) and 2 fp32 head weights; y==7 slice folds
// 6 BN const sets, copies Wxyz (sa3_w1 rows 0..2), zeroes pooled.
// ---------------------------------------------------------------------------
struct Prep2Args {
    const float* src[7]; void* dst[7];
    int K[7], N[7], Kp[7], tiles[7], isBF[7];
    const float* g[6]; const float* bb[6]; const float* mm[6]; const float* vv[6];
    float* sc[6]; float* sh[6]; int C[6];
    const float* xyzsrc; float* wxyz;
    float* pooled;
};

__global__ __launch_bounds__(256) void prep2_kernel(Prep2Args p) {
    int w = blockIdx.y;
    if (w < 7) {
        if ((int)blockIdx.x >= p.tiles[w]) return;
        int ntn = p.N[w] >> 5;
        int tk = blockIdx.x / ntn, tn = blockIdx.x - tk * ntn;
        int k0 = tk << 5, n0 = tn << 5;
        __shared__ float tile[32][33];
        int tx = threadIdx.x & 31, ty0 = threadIdx.x >> 5;
        const float* src = p.src[w];
        int N = p.N[w], K = p.K[w], Kp = p.Kp[w];
#pragma unroll
        for (int i = 0; i < 4; ++i) {
            int ty = ty0 + i * 8;
            int k = k0 + ty, n = n0 + tx;
            float v = 0.f;
            if (w == 2) {
                v = src[(k + 3) * N + n];  // skip xyz rows 0..2
            } else if (k < K) {
                v = src[k * N + n];
            }
            tile[ty][tx] = v;
        }
        __syncthreads();
#pragma unroll
        for (int i = 0; i < 4; ++i) {
            int ty = ty0 + i * 8;
            int n = n0 + ty, k = k0 + tx;
            if (p.isBF[w])
                ((ushort*)p.dst[w])[(size_t)n * Kp + k] = f2bf(tile[tx][ty]);
            else
                ((float*)p.dst[w])[(size_t)n * Kp + k] = tile[tx][ty];
        }
    } else {
        int idx = blockIdx.x * 256 + threadIdx.x;
        if (idx < 2240) {
            int s = 0, base = 0;
            for (s = 0; s < 6; ++s) {
                if (idx < base + p.C[s]) break;
                base += p.C[s];
            }
            int c = idx - base;
            float scv = p.g[s][c] * rsqrtf(p.vv[s][c] + 1e-5f);
            p.sc[s][c] = scv;
            p.sh[s][c] = p.bb[s][c] - p.mm[s][c] * scv;
        } else if (idx < 3008) {
            int j = idx - 2240;              // rows 0..2 of sa3_w1 = 768 elems
            p.wxyz[j] = p.xyzsrc[j];
        } else {
            int z = idx - 3008;
            if (z < 16384) p.pooled[z] = 0.f;
        }
    }
}

// ---------------------------------------------------------------------------
// SA1 fused (R10): per 128-row block (512 threads / 8 waves):
// l1 (K=6 VALU) -> F1; f2 (MFMA K=64) -> F2; f3 (MFMA K=128, W3 streamed
// into dead F1/W2s region); gate sigmoid; G[row,0..255] = bf16(f3*s).
// LDS ~68KB -> 2 blocks/CU.
// ---------------------------------------------------------------------------
__global__ __launch_bounds__(512) void sa1_fused(
    const float* __restrict__ xyz, const float* __restrict__ pts,
    const float* __restrict__ w1,
    const float* __restrict__ sc1, const float* __restrict__ sh1,
    const ushort* __restrict__ Wt2,
    const float* __restrict__ sc2, const float* __restrict__ sh2,
    const ushort* __restrict__ Wt3,
    const float* __restrict__ sc3, const float* __restrict__ sh3,
    const float* __restrict__ attw, const float* __restrict__ attb,
    ushort* __restrict__ G) {
    __shared__ ushort shm[16384];      // 32 KB: [F1 16K | W2s 16K] -> Bs
    __shared__ ushort F2[16384];       // 32 KB
    __shared__ float w1s[384];
    __shared__ float sc1s[64], sh1s[64];
    __shared__ float red[128 * 4];
    __shared__ float sig[128];
    ushort* F1 = shm;
    ushort* W2s = shm + 8192;
    ushort* Bs = shm;

    const int tid = threadIdx.x;
    const int bm0 = blockIdx.x * 128;
    const int wid = tid >> 6, ln = tid & 63;
    const int lm = ln & 15, q = ln >> 4;
    const int sx = lm & 7;

    if (tid < 384) w1s[tid] = w1[tid];
    if (tid < 64) { sc1s[tid] = sc1[tid]; sh1s[tid] = sh1[tid]; }
    const int srow = tid >> 3;
    const int sb = tid & 7;
    const int sgb = sb ^ (srow & 7);
#pragma unroll
    for (int l = 0; l < 2; ++l)
        gl_lds16(&Wt2[(size_t)(l * 64 + srow) * 64 + (sgb << 3)],
                 &W2s[l * 4096 + wid * 512]);
    __syncthreads();

#pragma unroll
    for (int i = 0; i < 2; ++i) {
        int chunk = tid + 512 * i;
        int row = chunk >> 3, blk = chunk & 7;
        int gr = bm0 + row;
        float i0 = xyz[gr * 3], i1 = xyz[gr * 3 + 1], i2 = xyz[gr * 3 + 2];
        float i3 = pts[gr * 3], i4 = pts[gr * 3 + 1], i5 = pts[gr * 3 + 2];
        ushort tmp[8];
#pragma unroll
        for (int j = 0; j < 8; ++j) {
            int c = blk * 8 + j;
            float a = i0 * w1s[c] + i1 * w1s[64 + c] + i2 * w1s[128 + c] +
                      i3 * w1s[192 + c] + i4 * w1s[256 + c] + i5 * w1s[320 + c];
            a = fmaxf(a * sc1s[c] + sh1s[c], 0.0f);
            tmp[j] = f2bf(a);
        }
        int slot = blk ^ (row & 7);
        *(uint4*)&F1[row * 64 + slot * 8] = *(uint4*)tmp;
    }
    asm volatile("s_waitcnt vmcnt(0)" ::: "memory");
    __syncthreads();  // F1 + W2s ready

    {
        const int wr2 = wid & 1, wc2 = wid >> 1;
        floatx4 acc2[4][2];
#pragma unroll
        for (int i = 0; i < 4; ++i)
#pragma unroll
            for (int j = 0; j < 2; ++j) acc2[i][j] = (floatx4){0.f, 0.f, 0.f, 0.f};
#pragma unroll
        for (int h = 0; h < 2; ++h) {
            const int slot = ((h << 2) | q) ^ sx;
            bf16x8 af[4], bf[2];
#pragma unroll
            for (int i = 0; i < 4; ++i)
                af[i] = *(const bf16x8*)(&F1[(wr2 * 64 + i * 16 + lm) * 64 + (slot << 3)]);
#pragma unroll
            for (int i = 0; i < 2; ++i)
                bf[i] = *(const bf16x8*)(&W2s[(wc2 * 32 + i * 16 + lm) * 64 + (slot << 3)]);
#pragma unroll
            for (int mi = 0; mi < 4; ++mi)
#pragma unroll
                for (int ni = 0; ni < 2; ++ni)
                    acc2[mi][ni] = __builtin_amdgcn_mfma_f32_16x16x32_bf16(
                        af[mi], bf[ni], acc2[mi][ni], 0, 0, 0);
        }
        float s2[2], t2[2];
#pragma unroll
        for (int ni = 0; ni < 2; ++ni) {
            int c = wc2 * 32 + ni * 16 + lm;
            s2[ni] = sc2[c]; t2[ni] = sh2[c];
        }
#pragma unroll
        for (int mi = 0; mi < 4; ++mi) {
#pragma unroll
            for (int ni = 0; ni < 2; ++ni) {
                int col = wc2 * 32 + ni * 16 + lm;
                int b = col >> 3;
#pragma unroll
                for (int r = 0; r < 4; ++r) {
                    int row = wr2 * 64 + mi * 16 + q * 4 + r;
                    float val = fmaxf(acc2[mi][ni][r] * s2[ni] + t2[ni], 0.0f);
                    F2[row * 128 + ((b ^ (row & 7)) << 3) + (col & 7)] = f2bf(val);
                }
            }
        }
    }
    __syncthreads();  // F2 ready; F1/W2s dead -> shm becomes Bs

    const int wr3 = wid & 1, wc3 = wid >> 1;
    floatx4 acc3[4][4];
#pragma unroll
    for (int i = 0; i < 4; ++i)
#pragma unroll
        for (int j = 0; j < 4; ++j) acc3[i][j] = (floatx4){0.f, 0.f, 0.f, 0.f};

    for (int kt = 0; kt < 128; kt += 64) {
#pragma unroll
        for (int l = 0; l < 4; ++l)
            gl_lds16(&Wt3[(size_t)(l * 64 + srow) * 128 + kt + (sgb << 3)],
                     &Bs[l * 4096 + wid * 512]);
        asm volatile("s_waitcnt vmcnt(0)" ::: "memory");
        __syncthreads();
#pragma unroll
        for (int h = 0; h < 2; ++h) {
            const int slotB = ((h << 2) | q) ^ sx;
            const int gbA = (kt >> 3) + (h << 2) + q;
            const int slotA = gbA ^ sx;
            bf16x8 af[4], bf[4];
#pragma unroll
            for (int i = 0; i < 4; ++i)
                af[i] = *(const bf16x8*)(&F2[(wr3 * 64 + i * 16 + lm) * 128 + (slotA << 3)]);
#pragma unroll
            for (int i = 0; i < 4; ++i)
                bf[i] = *(const bf16x8*)(&Bs[(wc3 * 64 + i * 16 + lm) * 64 + (slotB << 3)]);
#pragma unroll
            for (int mi = 0; mi < 4; ++mi)
#pragma unroll
                for (int ni = 0; ni < 4; ++ni)
                    acc3[mi][ni] = __builtin_amdgcn_mfma_f32_16x16x32_bf16(
                        af[mi], bf[ni], acc3[mi][ni], 0, 0, 0);
        }
        __syncthreads();
    }

    float s3[4], t3[4], aw[4];
#pragma unroll
    for (int ni = 0; ni < 4; ++ni) {
        int c = wc3 * 64 + ni * 16 + lm;
        s3[ni] = sc3[c]; t3[ni] = sh3[c]; aw[ni] = attw[c];
    }
#pragma unroll
    for (int mi = 0; mi < 4; ++mi) {
#pragma unroll
        for (int r = 0; r < 4; ++r) {
            int lrow = wr3 * 64 + mi * 16 + q * 4 + r;
            float p = 0.0f;
#pragma unroll
            for (int ni = 0; ni < 4; ++ni)
                p += fmaxf(acc3[mi][ni][r] * s3[ni] + t3[ni], 0.0f) * aw[ni];
#pragma unroll
            for (int o = 8; o > 0; o >>= 1) p += __shfl_xor(p, o, 16);
            if (lm == 0) red[lrow * 4 + wc3] = p;
        }
    }
    __syncthreads();
    if (tid < 128) {
        float sm = red[tid * 4] + red[tid * 4 + 1] + red[tid * 4 + 2] + red[tid * 4 + 3];
        sig[tid] = 1.0f / (1.0f + expf(-(sm + attb[0])));
    }
    __syncthreads();

    // write G (stride 256, gated features only; xyz handled in S1 epilogue)
#pragma unroll
    for (int mi = 0; mi < 4; ++mi) {
#pragma unroll
        for (int r = 0; r < 4; ++r) {
            int lrow = wr3 * 64 + mi * 16 + q * 4 + r;
            float sg = sig[lrow];
            size_t gb = (size_t)(bm0 + lrow) * 256;
#pragma unroll
            for (int ni = 0; ni < 4; ++ni) {
                int c = wc3 * 64 + ni * 16 + lm;
                float val = fmaxf(acc3[mi][ni][r] * s3[ni] + t3[ni], 0.0f);
                G[gb + c] = f2bf(val * sg);
            }
        }
    }
}

// ---------------------------------------------------------------------------
// GEMM — byte-identical R8 body (used for S2). DO NOT modify.
// ---------------------------------------------------------------------------
__global__ __launch_bounds__(256) void gemm_bn_relu(
    const ushort* __restrict__ A, const ushort* __restrict__ Wt,
    const float* __restrict__ scale, const float* __restrict__ shift,
    ushort* __restrict__ C, int N, int K, int numN, int ldc,
    const float* __restrict__ attw, float* __restrict__ logitsP) {
    __shared__ ushort As[128 * 64];
    __shared__ ushort Bs[128 * 64];
    const int tid = threadIdx.x;
    const int g8 = numN * 8;
    const int chunk = blockIdx.x / g8;
    const int rem = blockIdx.x - chunk * g8;
    const int nt = rem >> 3;
    const int xcd = rem & 7;
    const int bn0 = nt * 128;
    const int bm0 = (chunk * 8 + xcd) * 128;

    const int wid = tid >> 6, ln = tid & 63;
    const int wr = wid >> 1, wc = wid & 1;
    const int lm = ln & 15, q = ln >> 4;
    const int sx = lm & 7;

    floatx4 acc[4][4];
#pragma unroll
    for (int i = 0; i < 4; ++i)
#pragma unroll
        for (int j = 0; j < 4; ++j) acc[i][j] = (floatx4){0.f, 0.f, 0.f, 0.f};

    const int srow = tid >> 3;
    const int sb = tid & 7;
    const int sgb = sb ^ (srow & 7);
    const ushort* aP[4];
    const ushort* bP[4];
#pragma unroll
    for (int l = 0; l < 4; ++l) {
        int row = l * 32 + srow;
        aP[l] = &A[(size_t)(bm0 + row) * K + (sgb << 3)];
        bP[l] = &Wt[(size_t)(bn0 + row) * K + (sgb << 3)];
    }
    ushort* aL = &As[wid * 512];
    ushort* bL = &Bs[wid * 512];

    for (int kt = 0; kt < K; kt += 64) {
#pragma unroll
        for (int l = 0; l < 4; ++l) gl_lds16(aP[l], aL + l * 2048);
#pragma unroll
        for (int l = 0; l < 4; ++l) gl_lds16(bP[l], bL + l * 2048);
#pragma unroll
        for (int l = 0; l < 4; ++l) { aP[l] += 64; bP[l] += 64; }
        asm volatile("s_waitcnt vmcnt(0)" ::: "memory");
        __syncthreads();
#pragma unroll
        for (int h = 0; h < 2; ++h) {
            const int slot = ((h << 2) | q) ^ sx;
            bf16x8 af[4], bf[4];
#pragma unroll
            for (int i = 0; i < 4; ++i)
                af[i] = *(const bf16x8*)(&As[(wr * 64 + i * 16 + lm) * 64 + (slot << 3)]);
#pragma unroll
            for (int i = 0; i < 4; ++i)
                bf[i] = *(const bf16x8*)(&Bs[(wc * 64 + i * 16 + lm) * 64 + (slot << 3)]);
#pragma unroll
            for (int mi = 0; mi < 4; ++mi)
#pragma unroll
                for (int ni = 0; ni < 4; ++ni)
                    acc[mi][ni] = __builtin_amdgcn_mfma_f32_16x16x32_bf16(
                        af[mi], bf[ni], acc[mi][ni], 0, 0, 0);
        }
        __syncthreads();
    }

    float s[4], t[4], aw[4];
#pragma unroll
    for (int ni = 0; ni < 4; ++ni) {
        int gcol = bn0 + wc * 64 + ni * 16 + lm;
        s[ni] = scale[gcol];
        t[ni] = shift[gcol];
        aw[ni] = attw ? attw[gcol] : 0.0f;
    }
#pragma unroll
    for (int mi = 0; mi < 4; ++mi) {
        int grow0 = bm0 + wr * 64 + mi * 16 + q * 4;
#pragma unroll
        for (int r = 0; r < 4; ++r) {
            float p = 0.0f;
#pragma unroll
            for (int ni = 0; ni < 4; ++ni) {
                int gcol = bn0 + wc * 64 + ni * 16 + lm;
                float val = fmaxf(acc[mi][ni][r] * s[ni] + t[ni], 0.0f);
                C[(size_t)(grow0 + r) * ldc + gcol] = f2bf(val);
                p += val * aw[ni];
            }
            if (logitsP) {
#pragma unroll
                for (int o = 8; o > 0; o >>= 1) p += __shfl_xor(p, o, 16);
                if (lm == 0)
                    logitsP[(size_t)(nt * 2 + wc) * M_ROWS + grow0 + r] = p;
            }
        }
    }
}

// ---------------------------------------------------------------------------
// GEMM clone, BK=32 (S3 only). 16KB LDS, one MFMA phase per barrier pair
// (m97-prior). XOR key for 64B rows: stage sgb = sb ^ ((srow>>1)&3);
// read slot = q ^ ((lm>>1)&3) -> bank-quad 4*(lm&1) + (q^((lm>>1)&3))
// covers all 8 quads uniformly = 0 conflicts. Fused logits epilogue.
// ---------------------------------------------------------------------------
__global__ __launch_bounds__(256) void gemm_bk32(
    const ushort* __restrict__ A, const ushort* __restrict__ Wt,
    const float* __restrict__ scale, const float* __restrict__ shift,
    ushort* __restrict__ C, int N, int K, int numN, int ldc,
    const float* __restrict__ attw, float* __restrict__ logitsP) {
    __shared__ ushort As[128 * 32];
    __shared__ ushort Bs[128 * 32];
    const int tid = threadIdx.x;
    const int g8 = numN * 8;
    const int chunk = blockIdx.x / g8;
    const int rem = blockIdx.x - chunk * g8;
    const int nt = rem >> 3;
    const int xcd = rem & 7;
    const int bn0 = nt * 128;
    const int bm0 = (chunk * 8 + xcd) * 128;

    const int wid = tid >> 6, ln = tid & 63;
    const int wr = wid >> 1, wc = wid & 1;
    const int lm = ln & 15, q = ln >> 4;
    const int sx = (lm >> 1) & 3;

    floatx4 acc[4][4];
#pragma unroll
    for (int i = 0; i < 4; ++i)
#pragma unroll
        for (int j = 0; j < 4; ++j) acc[i][j] = (floatx4){0.f, 0.f, 0.f, 0.f};

    const int srow = tid >> 2;            // 0..63
    const int sb = tid & 3;               // LDS dest 16B-block
    const int sgb = sb ^ ((srow >> 1) & 3);  // global source block
    const ushort* aP[2];
    const ushort* bP[2];
#pragma unroll
    for (int l = 0; l < 2; ++l) {
        int row = l * 64 + srow;
        aP[l] = &A[(size_t)(bm0 + row) * K + (sgb << 3)];
        bP[l] = &Wt[(size_t)(bn0 + row) * K + (sgb << 3)];
    }
    ushort* aL = &As[wid * 512];
    ushort* bL = &Bs[wid * 512];

    for (int kt = 0; kt < K; kt += 32) {
#pragma unroll
        for (int l = 0; l < 2; ++l) gl_lds16(aP[l], aL + l * 2048);
#pragma unroll
        for (int l = 0; l < 2; ++l) gl_lds16(bP[l], bL + l * 2048);
#pragma unroll
        for (int l = 0; l < 2; ++l) { aP[l] += 32; bP[l] += 32; }
        asm volatile("s_waitcnt vmcnt(0)" ::: "memory");
        __syncthreads();
        {
            const int slot = q ^ sx;
            bf16x8 af[4], bf[4];
#pragma unroll
            for (int i = 0; i < 4; ++i)
                af[i] = *(const bf16x8*)(&As[(wr * 64 + i * 16 + lm) * 32 + (slot << 3)]);
#pragma unroll
            for (int i = 0; i < 4; ++i)
                bf[i] = *(const bf16x8*)(&Bs[(wc * 64 + i * 16 + lm) * 32 + (slot << 3)]);
#pragma unroll
            for (int mi = 0; mi < 4; ++mi)
#pragma unroll
                for (int ni = 0; ni < 4; ++ni)
                    acc[mi][ni] = __builtin_amdgcn_mfma_f32_16x16x32_bf16(
                        af[mi], bf[ni], acc[mi][ni], 0, 0, 0);
        }
        __syncthreads();
    }

    float s[4], t[4], aw[4];
#pragma unroll
    for (int ni = 0; ni < 4; ++ni) {
        int gcol = bn0 + wc * 64 + ni * 16 + lm;
        s[ni] = scale[gcol];
        t[ni] = shift[gcol];
        aw[ni] = attw ? attw[gcol] : 0.0f;
    }
#pragma unroll
    for (int mi = 0; mi < 4; ++mi) {
        int grow0 = bm0 + wr * 64 + mi * 16 + q * 4;
#pragma unroll
        for (int r = 0; r < 4; ++r) {
            float p = 0.0f;
#pragma unroll
            for (int ni = 0; ni < 4; ++ni) {
                int gcol = bn0 + wc * 64 + ni * 16 + lm;
                float val = fmaxf(acc[mi][ni][r] * s[ni] + t[ni], 0.0f);
                C[(size_t)(grow0 + r) * ldc + gcol] = f2bf(val);
                p += val * aw[ni];
            }
            if (logitsP) {
#pragma unroll
                for (int o = 8; o > 0; o >>= 1) p += __shfl_xor(p, o, 16);
                if (lm == 0)
                    logitsP[(size_t)(nt * 2 + wc) * M_ROWS + grow0 + r] = p;
            }
        }
    }
}

// ---------------------------------------------------------------------------
// GEMM clone for S1 only (R11): rank-3 xyz update pre-BN. Unchanged.
// ---------------------------------------------------------------------------
__global__ __launch_bounds__(256) void gemm_s1(
    const ushort* __restrict__ A, const ushort* __restrict__ Wt,
    const float* __restrict__ scale, const float* __restrict__ shift,
    ushort* __restrict__ C, int N, int K, int numN, int ldc,
    const float* __restrict__ xyzP, const float* __restrict__ Wxyz) {
    __shared__ ushort As[128 * 64];
    __shared__ ushort Bs[128 * 64];
    const int tid = threadIdx.x;
    const int g8 = numN * 8;
    const int chunk = blockIdx.x / g8;
    const int rem = blockIdx.x - chunk * g8;
    const int nt = rem >> 3;
    const int xcd = rem & 7;
    const int bn0 = nt * 128;
    const int bm0 = (chunk * 8 + xcd) * 128;

    const int wid = tid >> 6, ln = tid & 63;
    const int wr = wid >> 1, wc = wid & 1;
    const int lm = ln & 15, q = ln >> 4;
    const int sx = lm & 7;

    floatx4 acc[4][4];
#pragma unroll
    for (int i = 0; i < 4; ++i)
#pragma unroll
        for (int j = 0; j < 4; ++j) acc[i][j] = (floatx4){0.f, 0.f, 0.f, 0.f};

    const int srow = tid >> 3;
    const int sb = tid & 7;
    const int sgb = sb ^ (srow & 7);
    const ushort* aP[4];
    const ushort* bP[4];
#pragma unroll
    for (int l = 0; l < 4; ++l) {
        int row = l * 32 + srow;
        aP[l] = &A[(size_t)(bm0 + row) * K + (sgb << 3)];
        bP[l] = &Wt[(size_t)(bn0 + row) * K + (sgb << 3)];
    }
    ushort* aL = &As[wid * 512];
    ushort* bL = &Bs[wid * 512];

    for (int kt = 0; kt < K; kt += 64) {
#pragma unroll
        for (int l = 0; l < 4; ++l) gl_lds16(aP[l], aL + l * 2048);
#pragma unroll
        for (int l = 0; l < 4; ++l) gl_lds16(bP[l], bL + l * 2048);
#pragma unroll
        for (int l = 0; l < 4; ++l) { aP[l] += 64; bP[l] += 64; }
        asm volatile("s_waitcnt vmcnt(0)" ::: "memory");
        __syncthreads();
#pragma unroll
        for (int h = 0; h < 2; ++h) {
            const int slot = ((h << 2) | q) ^ sx;
            bf16x8 af[4], bf[4];
#pragma unroll
            for (int i = 0; i < 4; ++i)
                af[i] = *(const bf16x8*)(&As[(wr * 64 + i * 16 + lm) * 64 + (slot << 3)]);
#pragma unroll
            for (int i = 0; i < 4; ++i)
                bf[i] = *(const bf16x8*)(&Bs[(wc * 64 + i * 16 + lm) * 64 + (slot << 3)]);
#pragma unroll
            for (int mi = 0; mi < 4; ++mi)
#pragma unroll
                for (int ni = 0; ni < 4; ++ni)
                    acc[mi][ni] = __builtin_amdgcn_mfma_f32_16x16x32_bf16(
                        af[mi], bf[ni], acc[mi][ni], 0, 0, 0);
        }
        __syncthreads();
    }

    float s[4], t[4], wx0[4], wx1[4], wx2[4];
#pragma unroll
    for (int ni = 0; ni < 4; ++ni) {
        int gcol = bn0 + wc * 64 + ni * 16 + lm;
        s[ni] = scale[gcol];
        t[ni] = shift[gcol];
        wx0[ni] = Wxyz[gcol];
        wx1[ni] = Wxyz[256 + gcol];
        wx2[ni] = Wxyz[512 + gcol];
    }
#pragma unroll
    for (int mi = 0; mi < 4; ++mi) {
        int grow0 = bm0 + wr * 64 + mi * 16 + q * 4;
#pragma unroll
        for (int r = 0; r < 4; ++r) {
            int grow = grow0 + r;
            float x0 = xyzP[grow * 3], x1 = xyzP[grow * 3 + 1], x2 = xyzP[grow * 3 + 2];
#pragma unroll
            for (int ni = 0; ni < 4; ++ni) {
                int gcol = bn0 + wc * 64 + ni * 16 + lm;
                float a = acc[mi][ni][r] + x0 * wx0[ni] + x1 * wx1[ni] + x2 * wx2[ni];
                float val = fmaxf(a * s[ni] + t[ni], 0.0f);
                C[(size_t)grow * ldc + gcol] = f2bf(val);
            }
        }
    }
}

// ---------------------------------------------------------------------------
// Softmax over N=4096 per batch (logits = sum of 16 partial slices).
// ---------------------------------------------------------------------------
__global__ __launch_bounds__(1024) void softmax_kernel(
    const float* __restrict__ logitsP, float* __restrict__ alpha) {
    __shared__ float red[1024];
    int b = blockIdx.x, t = threadIdx.x;
    float4 v = (float4){0.f, 0.f, 0.f, 0.f};
#pragma unroll
    for (int j = 0; j < 16; ++j) {
        float4 pv = *(const float4*)&logitsP[(size_t)j * M_ROWS + b * 4096 + t * 4];
        v.x += pv.x; v.y += pv.y; v.z += pv.z; v.w += pv.w;
    }
    float mx = fmaxf(fmaxf(v.x, v.y), fmaxf(v.z, v.w));
    red[t] = mx;
    __syncthreads();
    for (int s = 512; s > 0; s >>= 1) {
        if (t < s) red[t] = fmaxf(red[t], red[t + s]);
        __syncthreads();
    }
    float M = red[0];
    __syncthreads();
    float e0 = expf(v.x - M), e1 = expf(v.y - M), e2 = expf(v.z - M), e3 = expf(v.w - M);
    red[t] = e0 + e1 + e2 + e3;
    __syncthreads();
    for (int s = 512; s > 0; s >>= 1) {
        if (t < s) red[t] += red[t + s];
        __syncthreads();
    }
    float inv = 1.0f / red[0];
    *(float4*)&alpha[b * 4096 + t * 4] = make_float4(e0 * inv, e1 * inv, e2 * inv, e3 * inv);
}

// ---------------------------------------------------------------------------
// Pool: pooled[b,c] = sum_n alpha[b,n]*g3[b,n,c]. 16B loads, 8 cols/thread:
// tid<128 -> n-half 0, tid>=128 -> n-half 1; halves combined in LDS, then
// one atomicAdd set per col-group. grid (1, 16 b, 32 nsplit) x 256.
// ---------------------------------------------------------------------------
__global__ __launch_bounds__(256) void pool_kernel(
    const ushort* __restrict__ g3, const float* __restrict__ alpha,
    float* __restrict__ pooled) {
    __shared__ float red[128 * 8];
    int t = threadIdx.x;
    int cg = t & 127, nh = t >> 7;
    int b = blockIdx.y;
    int n0 = blockIdx.z * 128 + nh * 64;
    const ushort* base = g3 + ((size_t)b * 4096 + n0) * 1024 + cg * 8;
    const float* al = alpha + b * 4096 + n0;
    float a[8] = {0.f, 0.f, 0.f, 0.f, 0.f, 0.f, 0.f, 0.f};
#pragma unroll 2
    for (int n = 0; n < 64; ++n) {
        float w = al[n];
        uint4 gv = *(const uint4*)&base[(size_t)n * 1024];
        a[0] += w * lo16(gv.x); a[1] += w * hi16(gv.x);
        a[2] += w * lo16(gv.y); a[3] += w * hi16(gv.y);
        a[4] += w * lo16(gv.z); a[5] += w * hi16(gv.z);
        a[6] += w * lo16(gv.w); a[7] += w * hi16(gv.w);
    }
    if (nh == 1) {
#pragma unroll
        for (int j = 0; j < 8; ++j) red[cg * 8 + j] = a[j];
    }
    __syncthreads();
    if (nh == 0) {
        float* pd = &pooled[b * 1024 + cg * 8];
#pragma unroll
        for (int j = 0; j < 8; ++j) atomicAdd(pd + j, a[j] + red[cg * 8 + j]);
    }
}

// ---------------------------------------------------------------------------
// Heads: wave-per-output, transposed fp32 weights (contiguous float4 reads)
// ---------------------------------------------------------------------------
__global__ __launch_bounds__(256) void head1_kernel(
    const float* __restrict__ pooled, const float* __restrict__ wt1,
    const float* __restrict__ g, const float* __restrict__ bb,
    const float* __restrict__ m, const float* __restrict__ v,
    float* __restrict__ h1) {
    int wv = (blockIdx.x * 256 + threadIdx.x) >> 6;
    int ln = threadIdx.x & 63;
    int b = wv >> 9, c = wv & 511;
    const float4* wp = (const float4*)&wt1[(size_t)c * 1024];
    const float4* pp = (const float4*)&pooled[b * 1024];
    float s = 0.f;
#pragma unroll
    for (int j = 0; j < 4; ++j) {
        float4 w4 = wp[ln * 4 + j], p4 = pp[ln * 4 + j];
        s += w4.x * p4.x + w4.y * p4.y + w4.z * p4.z + w4.w * p4.w;
    }
#pragma unroll
    for (int o = 32; o > 0; o >>= 1) s += __shfl_xor(s, o);
    if (ln == 0) {
        float sc = g[c] * rsqrtf(v[c] + 1e-5f);
        float sh = bb[c] - m[c] * sc;
        h1[b * 512 + c] = fmaxf(s * sc + sh, 0.0f);
    }
}

__global__ __launch_bounds__(256) void head2_kernel(
    const float* __restrict__ h1, const float* __restrict__ wt2,
    const float* __restrict__ g, const float* __restrict__ bb,
    const float* __restrict__ m, const float* __restrict__ v,
    float* __restrict__ h2) {
    int wv = (blockIdx.x * 256 + threadIdx.x) >> 6;
    int ln = threadIdx.x & 63;
    int b = wv >> 8, c = wv & 255;
    const float4* wp = (const float4*)&wt2[(size_t)c * 512];
    const float4* pp = (const float4*)&h1[b * 512];
    float s = 0.f;
#pragma unroll
    for (int j = 0; j < 2; ++j) {
        float4 w4 = wp[ln * 2 + j], p4 = pp[ln * 2 + j];
        s += w4.x * p4.x + w4.y * p4.y + w4.z * p4.z + w4.w * p4.w;
    }
#pragma unroll
    for (int o = 32; o > 0; o >>= 1) s += __shfl_xor(s, o);
    if (ln == 0) {
        float sc = g[c] * rsqrtf(v[c] + 1e-5f);
        float sh = bb[c] - m[c] * sc;
        h2[b * 256 + c] = fmaxf(s * sc + sh, 0.0f);
    }
}

__global__ __launch_bounds__(64) void head3_kernel(
    const float* __restrict__ h2, const float* __restrict__ pw,
    const float* __restrict__ pb, float* __restrict__ out) {
    int b = blockIdx.x, ln = threadIdx.x;
    float4 hv = *(const float4*)&h2[b * 256 + ln * 4];
    float4 wv = *(const float4*)&pw[ln * 4];
    float sum = hv.x * wv.x + hv.y * wv.y + hv.z * wv.z + hv.w * wv.w;
#pragma unroll
    for (int o = 32; o > 0; o >>= 1) sum += __shfl_xor(sum, o);
    if (ln == 0) out[b] = sum + pb[0];
}

// ---------------------------------------------------------------------------
extern "C" void kernel_launch(void* const* d_in, const int* in_sizes, int n_in,
                              void* d_out, int out_size, void* d_ws, size_t ws_size,
                              hipStream_t stream) {
    (void)in_sizes; (void)n_in; (void)out_size; (void)ws_size;
    const float* xyz = (const float*)d_in[0];
    const float* pts = (const float*)d_in[1];
    const float* sa1_w1 = (const float*)d_in[2];
    const float* bn1g = (const float*)d_in[3];
    const float* bn1b = (const float*)d_in[4];
    const float* bn1m = (const float*)d_in[5];
    const float* bn1v = (const float*)d_in[6];
    const float* sa1_w2 = (const float*)d_in[7];
    const float* bn2g = (const float*)d_in[8];
    const float* bn2b = (const float*)d_in[9];
    const float* bn2m = (const float*)d_in[10];
    const float* bn2v = (const float*)d_in[11];
    const float* sa1_w3 = (const float*)d_in[12];
    const float* bn3g = (const float*)d_in[13];
    const float* bn3b = (const float*)d_in[14];
    const float* bn3m = (const float*)d_in[15];
    const float* bn3v = (const float*)d_in[16];
    const float* att1w = (const float*)d_in[17];
    const float* att1b = (const float*)d_in[18];
    const float* sa3_w1 = (const float*)d_in[19];
    const float* s1g = (const float*)d_in[20];
    const float* s1b = (const float*)d_in[21];
    const float* s1m = (const float*)d_in[22];
    const float* s1v = (const float*)d_in[23];
    const float* sa3_w2 = (const float*)d_in[24];
    const float* s2g = (const float*)d_in[25];
    const float* s2b = (const float*)d_in[26];
    const float* s2m = (const float*)d_in[27];
    const float* s2v = (const float*)d_in[28];
    const float* sa3_w3 = (const float*)d_in[29];
    const float* s3g = (const float*)d_in[30];
    const float* s3b = (const float*)d_in[31];
    const float* s3m = (const float*)d_in[32];
    const float* s3v = (const float*)d_in[33];
    const float* att3w = (const float*)d_in[34];
    const float* fc1w = (const float*)d_in[35];
    const float* h1g = (const float*)d_in[36];
    const float* h1b = (const float*)d_in[37];
    const float* h1m = (const float*)d_in[38];
    const float* h1v = (const float*)d_in[39];
    const float* fc2w = (const float*)d_in[40];
    const float* h2g = (const float*)d_in[41];
    const float* h2b = (const float*)d_in[42];
    const float* h2m = (const float*)d_in[43];
    const float* h2v = (const float*)d_in[44];
    const float* predw = (const float*)d_in[45];
    const float* predb = (const float*)d_in[46];
    float* out = (float*)d_out;

    // ---- workspace ----
    char* wsb = (char*)d_ws;
    size_t off = 0;
    auto alloc = [&](size_t bytes) -> void* {
        off = (off + 255) & ~(size_t)255;
        void* p = wsb + off;
        off += bytes;
        return p;
    };
    ushort* Wt2 = (ushort*)alloc(128 * 64 * 2);
    ushort* Wt3 = (ushort*)alloc(256 * 128 * 2);
    ushort* WtS1 = (ushort*)alloc(256 * 256 * 2);
    ushort* WtS2 = (ushort*)alloc(512 * 256 * 2);
    ushort* WtS3 = (ushort*)alloc(1024 * 512 * 2);
    float* wt1 = (float*)alloc(512 * 1024 * 4);
    float* wt2 = (float*)alloc(256 * 512 * 4);
    float* wxyz = (float*)alloc(768 * 4);
    float* sc1 = (float*)alloc(64 * 4);   float* sh1 = (float*)alloc(64 * 4);
    float* sc2 = (float*)alloc(128 * 4);  float* sh2 = (float*)alloc(128 * 4);
    float* sc3 = (float*)alloc(256 * 4);  float* sh3 = (float*)alloc(256 * 4);
    float* scS1 = (float*)alloc(256 * 4); float* shS1 = (float*)alloc(256 * 4);
    float* scS2 = (float*)alloc(512 * 4); float* shS2 = (float*)alloc(512 * 4);
    float* scS3 = (float*)alloc(1024 * 4); float* shS3 = (float*)alloc(1024 * 4);
    float* logitsP = (float*)alloc((size_t)16 * M_ROWS * 4);
    float* alpha = (float*)alloc((size_t)M_ROWS * 4);
    float* pooled = (float*)alloc(16 * 1024 * 4);
    float* h1buf = (float*)alloc(16 * 512 * 4);
    float* h2buf = (float*)alloc(16 * 256 * 4);

    // big region, overlaid by live range. G stride 256 (32 MB).
    off = (off + MB - 1) & ~(MB - 1);
    char* bigA = wsb + off;            // 128 MB
    char* bigB = bigA + 128 * MB;      // 64 MB
    ushort* G  = (ushort*)(bigA);             // 32 MB  [fused, S1)
    ushort* g1 = (ushort*)(bigA + 32 * MB);   // 32 MB  [S1, S2)
    ushort* g3 = (ushort*)(bigA);             // 128 MB [S3, pool)
    ushort* g2 = (ushort*)(bigB);             // 64 MB  [S2, S3)

    // ---- prep2 ----
    Prep2Args pa;
    const float* srcs[7] = {sa1_w2, sa1_w3, sa3_w1, sa3_w2, sa3_w3, fc1w, fc2w};
    void* dsts[7] = {Wt2, Wt3, WtS1, WtS2, WtS3, wt1, wt2};
    int Ks[7] = {64, 128, 256, 256, 512, 1024, 512};
    int Ns[7] = {128, 256, 256, 512, 1024, 512, 256};
    int Kps[7] = {64, 128, 256, 256, 512, 1024, 512};
    int isBF[7] = {1, 1, 1, 1, 1, 0, 0};
    int maxTiles = 0;
    for (int i = 0; i < 7; ++i) {
        pa.src[i] = srcs[i]; pa.dst[i] = dsts[i];
        pa.K[i] = Ks[i]; pa.N[i] = Ns[i]; pa.Kp[i] = Kps[i];
        pa.isBF[i] = isBF[i];
        pa.tiles[i] = (Kps[i] >> 5) * (Ns[i] >> 5);
        if (pa.tiles[i] > maxTiles) maxTiles = pa.tiles[i];
    }
    const float* gs[6] = {bn1g, bn2g, bn3g, s1g, s2g, s3g};
    const float* bbs[6] = {bn1b, bn2b, bn3b, s1b, s2b, s3b};
    const float* mms[6] = {bn1m, bn2m, bn3m, s1m, s2m, s3m};
    const float* vvs[6] = {bn1v, bn2v, bn3v, s1v, s2v, s3v};
    float* scs[6] = {sc1, sc2, sc3, scS1, scS2, scS3};
    float* shs[6] = {sh1, sh2, sh3, shS1, shS2, shS3};
    int Cs6[6] = {64, 128, 256, 256, 512, 1024};
    for (int i = 0; i < 6; ++i) {
        pa.g[i] = gs[i]; pa.bb[i] = bbs[i]; pa.mm[i] = mms[i]; pa.vv[i] = vvs[i];
        pa.sc[i] = scs[i]; pa.sh[i] = shs[i]; pa.C[i] = Cs6[i];
    }
    pa.xyzsrc = sa3_w1;
    pa.wxyz = wxyz;
    pa.pooled = pooled;
    prep2_kernel<<<dim3(maxTiles, 8), 256, 0, stream>>>(pa);

    // ---- SA1 fused front: xyz/pts -> G [M,256] ----
    sa1_fused<<<M_ROWS / 128, 512, 0, stream>>>(
        xyz, pts, sa1_w1, sc1, sh1, Wt2, sc2, sh2, Wt3, sc3, sh3,
        att1w, att1b, G);
    // ---- SA3 ----
    gemm_s1<<<512 * 2, 256, 0, stream>>>(G, WtS1, scS1, shS1, g1, 256, 256, 2, 256, xyz, wxyz);
    gemm_bn_relu<<<512 * 4, 256, 0, stream>>>(g1, WtS2, scS2, shS2, g2, 512, 256, 4, 512, nullptr, nullptr);
    // S3: BK=32 experiment (m97-prior)
    gemm_bk32<<<512 * 8, 256, 0, stream>>>(g2, WtS3, scS3, shS3, g3, 1024, 512, 8, 1024, att3w, logitsP);
    // ---- attention pooling ----
    softmax_kernel<<<16, 1024, 0, stream>>>(logitsP, alpha);
    pool_kernel<<<dim3(1, 16, 32), 256, 0, stream>>>(g3, alpha, pooled);
    // ---- head ----
    head1_kernel<<<2048, 256, 0, stream>>>(pooled, wt1, h1g, h1b, h1m, h1v, h1buf);
    head2_kernel<<<1024, 256, 0, stream>>>(h1buf, wt2, h2g, h2b, h2m, h2v, h2buf);
    head3_kernel<<<16, 64, 0, stream>>>(h2buf, predw, predb, out);
}

// Round 13
// 357.469 us; speedup vs baseline: 1.0958x; 1.0958x over previous
//
#include <hip/hip_runtime.h>

// ---------------------------------------------------------------------------
// PointNet2-AT inference pipeline, bf16 MFMA GEMMs + fp32 epilogues.
// B=16, N=4096 -> M = 65536 rows everywhere.
// R5 GEMM config (proven): 128x128 tile, BK=64, XOR bank-deswizzle,
//   global_load_lds 16B, XCD-aware grid swizzle, 0 bank conflicts.
// R8: SA1 megafusion. R11: GEMM-body isolation (clone per variant). 359.6us.
// R12 FAILED: BK=32 S3 (+18us: doubled barrier drains at 2.4 blk/CU beats
//   finer overlap) and LDS-combine pool (+~14us). Tile space for S3 now
//   exhausted: {128^2,BK64} > {128^2,BK32} > {256x128}. The 107us/642TF S3
//   is the 2-barrier K-loop structure's plateau (per m97/m131-m141, going
//   past requires hand-asm-style fine-vmcnt K-loop, not expressible in HIP).
// R13: exact R11 restore (best measured config for every component).
// ---------------------------------------------------------------------------

#define M_ROWS 65536
#define MB ((size_t)1 << 20)

typedef __bf16 bf16x8 __attribute__((ext_vector_type(8)));
typedef float floatx4 __attribute__((ext_vector_type(4)));

__device__ __forceinline__ float b2f(ushort u) {
    unsigned int x = ((unsigned int)u) << 16;
    float f;
    __builtin_memcpy(&f, &x, 4);
    return f;
}
__device__ __forceinline__ ushort f2bf(float f) {
    unsigned int x;
    __builtin_memcpy(&x, &f, 4);
    unsigned int r = x + 0x7fffu + ((x >> 16) & 1u);  // RNE
    return (ushort)(r >> 16);
}

// async global->LDS, 16B per lane; LDS dest = wave-uniform base + lane*16
__device__ __forceinline__ void gl_lds16(const ushort* g, ushort* l) {
    __builtin_amdgcn_global_load_lds(
        (const __attribute__((address_space(1))) unsigned int*)g,
        (__attribute__((address_space(3))) unsigned int*)l, 16, 0, 0);
}

// ---------------------------------------------------------------------------
// Prep2: LDS-tiled transpose of 5 bf16 GEMM weights (w==2 = sa3_w1 rows
// 3..258 only -> WtS1 [256][256]) and 2 fp32 head weights; y==7 slice folds
// 6 BN const sets, copies Wxyz (sa3_w1 rows 0..2), zeroes pooled.
// ---------------------------------------------------------------------------
struct Prep2Args {
    const float* src[7]; void* dst[7];
    int K[7], N[7], Kp[7], tiles[7], isBF[7];
    const float* g[6]; const float* bb[6]; const float* mm[6]; const float* vv[6];
    float* sc[6]; float* sh[6]; int C[6];
    const float* xyzsrc; float* wxyz;
    float* pooled;
};

__global__ __launch_bounds__(256) void prep2_kernel(Prep2Args p) {
    int w = blockIdx.y;
    if (w < 7) {
        if ((int)blockIdx.x >= p.tiles[w]) return;
        int ntn = p.N[w] >> 5;
        int tk = blockIdx.x / ntn, tn = blockIdx.x - tk * ntn;
        int k0 = tk << 5, n0 = tn << 5;
        __shared__ float tile[32][33];
        int tx = threadIdx.x & 31, ty0 = threadIdx.x >> 5;
        const float* src = p.src[w];
        int N = p.N[w], K = p.K[w], Kp = p.Kp[w];
#pragma unroll
        for (int i = 0; i < 4; ++i) {
            int ty = ty0 + i * 8;
            int k = k0 + ty, n = n0 + tx;
            float v = 0.f;
            if (w == 2) {
                v = src[(k + 3) * N + n];  // skip xyz rows 0..2
            } else if (k < K) {
                v = src[k * N + n];
            }
            tile[ty][tx] = v;
        }
        __syncthreads();
#pragma unroll
        for (int i = 0; i < 4; ++i) {
            int ty = ty0 + i * 8;
            int n = n0 + ty, k = k0 + tx;
            if (p.isBF[w])
                ((ushort*)p.dst[w])[(size_t)n * Kp + k] = f2bf(tile[tx][ty]);
            else
                ((float*)p.dst[w])[(size_t)n * Kp + k] = tile[tx][ty];
        }
    } else {
        int idx = blockIdx.x * 256 + threadIdx.x;
        if (idx < 2240) {
            int s = 0, base = 0;
            for (s = 0; s < 6; ++s) {
                if (idx < base + p.C[s]) break;
                base += p.C[s];
            }
            int c = idx - base;
            float scv = p.g[s][c] * rsqrtf(p.vv[s][c] + 1e-5f);
            p.sc[s][c] = scv;
            p.sh[s][c] = p.bb[s][c] - p.mm[s][c] * scv;
        } else if (idx < 3008) {
            int j = idx - 2240;              // rows 0..2 of sa3_w1 = 768 elems
            p.wxyz[j] = p.xyzsrc[j];
        } else {
            int z = idx - 3008;
            if (z < 16384) p.pooled[z] = 0.f;
        }
    }
}

// ---------------------------------------------------------------------------
// SA1 fused (R10): per 128-row block (512 threads / 8 waves):
// l1 (K=6 VALU) -> F1; f2 (MFMA K=64) -> F2; f3 (MFMA K=128, W3 streamed
// into dead F1/W2s region); gate sigmoid; G[row,0..255] = bf16(f3*s).
// LDS ~68KB -> 2 blocks/CU.
// ---------------------------------------------------------------------------
__global__ __launch_bounds__(512) void sa1_fused(
    const float* __restrict__ xyz, const float* __restrict__ pts,
    const float* __restrict__ w1,
    const float* __restrict__ sc1, const float* __restrict__ sh1,
    const ushort* __restrict__ Wt2,
    const float* __restrict__ sc2, const float* __restrict__ sh2,
    const ushort* __restrict__ Wt3,
    const float* __restrict__ sc3, const float* __restrict__ sh3,
    const float* __restrict__ attw, const float* __restrict__ attb,
    ushort* __restrict__ G) {
    __shared__ ushort shm[16384];      // 32 KB: [F1 16K | W2s 16K] -> Bs
    __shared__ ushort F2[16384];       // 32 KB
    __shared__ float w1s[384];
    __shared__ float sc1s[64], sh1s[64];
    __shared__ float red[128 * 4];
    __shared__ float sig[128];
    ushort* F1 = shm;
    ushort* W2s = shm + 8192;
    ushort* Bs = shm;

    const int tid = threadIdx.x;
    const int bm0 = blockIdx.x * 128;
    const int wid = tid >> 6, ln = tid & 63;
    const int lm = ln & 15, q = ln >> 4;
    const int sx = lm & 7;

    if (tid < 384) w1s[tid] = w1[tid];
    if (tid < 64) { sc1s[tid] = sc1[tid]; sh1s[tid] = sh1[tid]; }
    const int srow = tid >> 3;
    const int sb = tid & 7;
    const int sgb = sb ^ (srow & 7);
#pragma unroll
    for (int l = 0; l < 2; ++l)
        gl_lds16(&Wt2[(size_t)(l * 64 + srow) * 64 + (sgb << 3)],
                 &W2s[l * 4096 + wid * 512]);
    __syncthreads();

#pragma unroll
    for (int i = 0; i < 2; ++i) {
        int chunk = tid + 512 * i;
        int row = chunk >> 3, blk = chunk & 7;
        int gr = bm0 + row;
        float i0 = xyz[gr * 3], i1 = xyz[gr * 3 + 1], i2 = xyz[gr * 3 + 2];
        float i3 = pts[gr * 3], i4 = pts[gr * 3 + 1], i5 = pts[gr * 3 + 2];
        ushort tmp[8];
#pragma unroll
        for (int j = 0; j < 8; ++j) {
            int c = blk * 8 + j;
            float a = i0 * w1s[c] + i1 * w1s[64 + c] + i2 * w1s[128 + c] +
                      i3 * w1s[192 + c] + i4 * w1s[256 + c] + i5 * w1s[320 + c];
            a = fmaxf(a * sc1s[c] + sh1s[c], 0.0f);
            tmp[j] = f2bf(a);
        }
        int slot = blk ^ (row & 7);
        *(uint4*)&F1[row * 64 + slot * 8] = *(uint4*)tmp;
    }
    asm volatile("s_waitcnt vmcnt(0)" ::: "memory");
    __syncthreads();  // F1 + W2s ready

    {
        const int wr2 = wid & 1, wc2 = wid >> 1;
        floatx4 acc2[4][2];
#pragma unroll
        for (int i = 0; i < 4; ++i)
#pragma unroll
            for (int j = 0; j < 2; ++j) acc2[i][j] = (floatx4){0.f, 0.f, 0.f, 0.f};
#pragma unroll
        for (int h = 0; h < 2; ++h) {
            const int slot = ((h << 2) | q) ^ sx;
            bf16x8 af[4], bf[2];
#pragma unroll
            for (int i = 0; i < 4; ++i)
                af[i] = *(const bf16x8*)(&F1[(wr2 * 64 + i * 16 + lm) * 64 + (slot << 3)]);
#pragma unroll
            for (int i = 0; i < 2; ++i)
                bf[i] = *(const bf16x8*)(&W2s[(wc2 * 32 + i * 16 + lm) * 64 + (slot << 3)]);
#pragma unroll
            for (int mi = 0; mi < 4; ++mi)
#pragma unroll
                for (int ni = 0; ni < 2; ++ni)
                    acc2[mi][ni] = __builtin_amdgcn_mfma_f32_16x16x32_bf16(
                        af[mi], bf[ni], acc2[mi][ni], 0, 0, 0);
        }
        float s2[2], t2[2];
#pragma unroll
        for (int ni = 0; ni < 2; ++ni) {
            int c = wc2 * 32 + ni * 16 + lm;
            s2[ni] = sc2[c]; t2[ni] = sh2[c];
        }
#pragma unroll
        for (int mi = 0; mi < 4; ++mi) {
#pragma unroll
            for (int ni = 0; ni < 2; ++ni) {
                int col = wc2 * 32 + ni * 16 + lm;
                int b = col >> 3;
#pragma unroll
                for (int r = 0; r < 4; ++r) {
                    int row = wr2 * 64 + mi * 16 + q * 4 + r;
                    float val = fmaxf(acc2[mi][ni][r] * s2[ni] + t2[ni], 0.0f);
                    F2[row * 128 + ((b ^ (row & 7)) << 3) + (col & 7)] = f2bf(val);
                }
            }
        }
    }
    __syncthreads();  // F2 ready; F1/W2s dead -> shm becomes Bs

    const int wr3 = wid & 1, wc3 = wid >> 1;
    floatx4 acc3[4][4];
#pragma unroll
    for (int i = 0; i < 4; ++i)
#pragma unroll
        for (int j = 0; j < 4; ++j) acc3[i][j] = (floatx4){0.f, 0.f, 0.f, 0.f};

    for (int kt = 0; kt < 128; kt += 64) {
#pragma unroll
        for (int l = 0; l < 4; ++l)
            gl_lds16(&Wt3[(size_t)(l * 64 + srow) * 128 + kt + (sgb << 3)],
                     &Bs[l * 4096 + wid * 512]);
        asm volatile("s_waitcnt vmcnt(0)" ::: "memory");
        __syncthreads();
#pragma unroll
        for (int h = 0; h < 2; ++h) {
            const int slotB = ((h << 2) | q) ^ sx;
            const int gbA = (kt >> 3) + (h << 2) + q;
            const int slotA = gbA ^ sx;
            bf16x8 af[4], bf[4];
#pragma unroll
            for (int i = 0; i < 4; ++i)
                af[i] = *(const bf16x8*)(&F2[(wr3 * 64 + i * 16 + lm) * 128 + (slotA << 3)]);
#pragma unroll
            for (int i = 0; i < 4; ++i)
                bf[i] = *(const bf16x8*)(&Bs[(wc3 * 64 + i * 16 + lm) * 64 + (slotB << 3)]);
#pragma unroll
            for (int mi = 0; mi < 4; ++mi)
#pragma unroll
                for (int ni = 0; ni < 4; ++ni)
                    acc3[mi][ni] = __builtin_amdgcn_mfma_f32_16x16x32_bf16(
                        af[mi], bf[ni], acc3[mi][ni], 0, 0, 0);
        }
        __syncthreads();
    }

    float s3[4], t3[4], aw[4];
#pragma unroll
    for (int ni = 0; ni < 4; ++ni) {
        int c = wc3 * 64 + ni * 16 + lm;
        s3[ni] = sc3[c]; t3[ni] = sh3[c]; aw[ni] = attw[c];
    }
#pragma unroll
    for (int mi = 0; mi < 4; ++mi) {
#pragma unroll
        for (int r = 0; r < 4; ++r) {
            int lrow = wr3 * 64 + mi * 16 + q * 4 + r;
            float p = 0.0f;
#pragma unroll
            for (int ni = 0; ni < 4; ++ni)
                p += fmaxf(acc3[mi][ni][r] * s3[ni] + t3[ni], 0.0f) * aw[ni];
#pragma unroll
            for (int o = 8; o > 0; o >>= 1) p += __shfl_xor(p, o, 16);
            if (lm == 0) red[lrow * 4 + wc3] = p;
        }
    }
    __syncthreads();
    if (tid < 128) {
        float sm = red[tid * 4] + red[tid * 4 + 1] + red[tid * 4 + 2] + red[tid * 4 + 3];
        sig[tid] = 1.0f / (1.0f + expf(-(sm + attb[0])));
    }
    __syncthreads();

    // write G (stride 256, gated features only; xyz handled in S1 epilogue)
#pragma unroll
    for (int mi = 0; mi < 4; ++mi) {
#pragma unroll
        for (int r = 0; r < 4; ++r) {
            int lrow = wr3 * 64 + mi * 16 + q * 4 + r;
            float sg = sig[lrow];
            size_t gb = (size_t)(bm0 + lrow) * 256;
#pragma unroll
            for (int ni = 0; ni < 4; ++ni) {
                int c = wc3 * 64 + ni * 16 + lm;
                float val = fmaxf(acc3[mi][ni][r] * s3[ni] + t3[ni], 0.0f);
                G[gb + c] = f2bf(val * sg);
            }
        }
    }
}

// ---------------------------------------------------------------------------
// GEMM — byte-identical R8 body (used for S2 and S3). DO NOT modify.
// ---------------------------------------------------------------------------
__global__ __launch_bounds__(256) void gemm_bn_relu(
    const ushort* __restrict__ A, const ushort* __restrict__ Wt,
    const float* __restrict__ scale, const float* __restrict__ shift,
    ushort* __restrict__ C, int N, int K, int numN, int ldc,
    const float* __restrict__ attw, float* __restrict__ logitsP) {
    __shared__ ushort As[128 * 64];
    __shared__ ushort Bs[128 * 64];
    const int tid = threadIdx.x;
    const int g8 = numN * 8;
    const int chunk = blockIdx.x / g8;
    const int rem = blockIdx.x - chunk * g8;
    const int nt = rem >> 3;
    const int xcd = rem & 7;
    const int bn0 = nt * 128;
    const int bm0 = (chunk * 8 + xcd) * 128;

    const int wid = tid >> 6, ln = tid & 63;
    const int wr = wid >> 1, wc = wid & 1;
    const int lm = ln & 15, q = ln >> 4;
    const int sx = lm & 7;

    floatx4 acc[4][4];
#pragma unroll
    for (int i = 0; i < 4; ++i)
#pragma unroll
        for (int j = 0; j < 4; ++j) acc[i][j] = (floatx4){0.f, 0.f, 0.f, 0.f};

    const int srow = tid >> 3;
    const int sb = tid & 7;
    const int sgb = sb ^ (srow & 7);
    const ushort* aP[4];
    const ushort* bP[4];
#pragma unroll
    for (int l = 0; l < 4; ++l) {
        int row = l * 32 + srow;
        aP[l] = &A[(size_t)(bm0 + row) * K + (sgb << 3)];
        bP[l] = &Wt[(size_t)(bn0 + row) * K + (sgb << 3)];
    }
    ushort* aL = &As[wid * 512];
    ushort* bL = &Bs[wid * 512];

    for (int kt = 0; kt < K; kt += 64) {
#pragma unroll
        for (int l = 0; l < 4; ++l) gl_lds16(aP[l], aL + l * 2048);
#pragma unroll
        for (int l = 0; l < 4; ++l) gl_lds16(bP[l], bL + l * 2048);
#pragma unroll
        for (int l = 0; l < 4; ++l) { aP[l] += 64; bP[l] += 64; }
        asm volatile("s_waitcnt vmcnt(0)" ::: "memory");
        __syncthreads();
#pragma unroll
        for (int h = 0; h < 2; ++h) {
            const int slot = ((h << 2) | q) ^ sx;
            bf16x8 af[4], bf[4];
#pragma unroll
            for (int i = 0; i < 4; ++i)
                af[i] = *(const bf16x8*)(&As[(wr * 64 + i * 16 + lm) * 64 + (slot << 3)]);
#pragma unroll
            for (int i = 0; i < 4; ++i)
                bf[i] = *(const bf16x8*)(&Bs[(wc * 64 + i * 16 + lm) * 64 + (slot << 3)]);
#pragma unroll
            for (int mi = 0; mi < 4; ++mi)
#pragma unroll
                for (int ni = 0; ni < 4; ++ni)
                    acc[mi][ni] = __builtin_amdgcn_mfma_f32_16x16x32_bf16(
                        af[mi], bf[ni], acc[mi][ni], 0, 0, 0);
        }
        __syncthreads();
    }

    float s[4], t[4], aw[4];
#pragma unroll
    for (int ni = 0; ni < 4; ++ni) {
        int gcol = bn0 + wc * 64 + ni * 16 + lm;
        s[ni] = scale[gcol];
        t[ni] = shift[gcol];
        aw[ni] = attw ? attw[gcol] : 0.0f;
    }
#pragma unroll
    for (int mi = 0; mi < 4; ++mi) {
        int grow0 = bm0 + wr * 64 + mi * 16 + q * 4;
#pragma unroll
        for (int r = 0; r < 4; ++r) {
            float p = 0.0f;
#pragma unroll
            for (int ni = 0; ni < 4; ++ni) {
                int gcol = bn0 + wc * 64 + ni * 16 + lm;
                float val = fmaxf(acc[mi][ni][r] * s[ni] + t[ni], 0.0f);
                C[(size_t)(grow0 + r) * ldc + gcol] = f2bf(val);
                p += val * aw[ni];
            }
            if (logitsP) {
#pragma unroll
                for (int o = 8; o > 0; o >>= 1) p += __shfl_xor(p, o, 16);
                if (lm == 0)
                    logitsP[(size_t)(nt * 2 + wc) * M_ROWS + grow0 + r] = p;
            }
        }
    }
}

// ---------------------------------------------------------------------------
// GEMM clone for S1 only (R11): rank-3 xyz update pre-BN.
// ---------------------------------------------------------------------------
__global__ __launch_bounds__(256) void gemm_s1(
    const ushort* __restrict__ A, const ushort* __restrict__ Wt,
    const float* __restrict__ scale, const float* __restrict__ shift,
    ushort* __restrict__ C, int N, int K, int numN, int ldc,
    const float* __restrict__ xyzP, const float* __restrict__ Wxyz) {
    __shared__ ushort As[128 * 64];
    __shared__ ushort Bs[128 * 64];
    const int tid = threadIdx.x;
    const int g8 = numN * 8;
    const int chunk = blockIdx.x / g8;
    const int rem = blockIdx.x - chunk * g8;
    const int nt = rem >> 3;
    const int xcd = rem & 7;
    const int bn0 = nt * 128;
    const int bm0 = (chunk * 8 + xcd) * 128;

    const int wid = tid >> 6, ln = tid & 63;
    const int wr = wid >> 1, wc = wid & 1;
    const int lm = ln & 15, q = ln >> 4;
    const int sx = lm & 7;

    floatx4 acc[4][4];
#pragma unroll
    for (int i = 0; i < 4; ++i)
#pragma unroll
        for (int j = 0; j < 4; ++j) acc[i][j] = (floatx4){0.f, 0.f, 0.f, 0.f};

    const int srow = tid >> 3;
    const int sb = tid & 7;
    const int sgb = sb ^ (srow & 7);
    const ushort* aP[4];
    const ushort* bP[4];
#pragma unroll
    for (int l = 0; l < 4; ++l) {
        int row = l * 32 + srow;
        aP[l] = &A[(size_t)(bm0 + row) * K + (sgb << 3)];
        bP[l] = &Wt[(size_t)(bn0 + row) * K + (sgb << 3)];
    }
    ushort* aL = &As[wid * 512];
    ushort* bL = &Bs[wid * 512];

    for (int kt = 0; kt < K; kt += 64) {
#pragma unroll
        for (int l = 0; l < 4; ++l) gl_lds16(aP[l], aL + l * 2048);
#pragma unroll
        for (int l = 0; l < 4; ++l) gl_lds16(bP[l], bL + l * 2048);
#pragma unroll
        for (int l = 0; l < 4; ++l) { aP[l] += 64; bP[l] += 64; }
        asm volatile("s_waitcnt vmcnt(0)" ::: "memory");
        __syncthreads();
#pragma unroll
        for (int h = 0; h < 2; ++h) {
            const int slot = ((h << 2) | q) ^ sx;
            bf16x8 af[4], bf[4];
#pragma unroll
            for (int i = 0; i < 4; ++i)
                af[i] = *(const bf16x8*)(&As[(wr * 64 + i * 16 + lm) * 64 + (slot << 3)]);
#pragma unroll
            for (int i = 0; i < 4; ++i)
                bf[i] = *(const bf16x8*)(&Bs[(wc * 64 + i * 16 + lm) * 64 + (slot << 3)]);
#pragma unroll
            for (int mi = 0; mi < 4; ++mi)
#pragma unroll
                for (int ni = 0; ni < 4; ++ni)
                    acc[mi][ni] = __builtin_amdgcn_mfma_f32_16x16x32_bf16(
                        af[mi], bf[ni], acc[mi][ni], 0, 0, 0);
        }
        __syncthreads();
    }

    float s[4], t[4], wx0[4], wx1[4], wx2[4];
#pragma unroll
    for (int ni = 0; ni < 4; ++ni) {
        int gcol = bn0 + wc * 64 + ni * 16 + lm;
        s[ni] = scale[gcol];
        t[ni] = shift[gcol];
        wx0[ni] = Wxyz[gcol];
        wx1[ni] = Wxyz[256 + gcol];
        wx2[ni] = Wxyz[512 + gcol];
    }
#pragma unroll
    for (int mi = 0; mi < 4; ++mi) {
        int grow0 = bm0 + wr * 64 + mi * 16 + q * 4;
#pragma unroll
        for (int r = 0; r < 4; ++r) {
            int grow = grow0 + r;
            float x0 = xyzP[grow * 3], x1 = xyzP[grow * 3 + 1], x2 = xyzP[grow * 3 + 2];
#pragma unroll
            for (int ni = 0; ni < 4; ++ni) {
                int gcol = bn0 + wc * 64 + ni * 16 + lm;
                float a = acc[mi][ni][r] + x0 * wx0[ni] + x1 * wx1[ni] + x2 * wx2[ni];
                float val = fmaxf(a * s[ni] + t[ni], 0.0f);
                C[(size_t)grow * ldc + gcol] = f2bf(val);
            }
        }
    }
}

// ---------------------------------------------------------------------------
// Softmax over N=4096 per batch (logits = sum of 16 partial slices).
// ---------------------------------------------------------------------------
__global__ __launch_bounds__(1024) void softmax_kernel(
    const float* __restrict__ logitsP, float* __restrict__ alpha) {
    __shared__ float red[1024];
    int b = blockIdx.x, t = threadIdx.x;
    float4 v = (float4){0.f, 0.f, 0.f, 0.f};
#pragma unroll
    for (int j = 0; j < 16; ++j) {
        float4 pv = *(const float4*)&logitsP[(size_t)j * M_ROWS + b * 4096 + t * 4];
        v.x += pv.x; v.y += pv.y; v.z += pv.z; v.w += pv.w;
    }
    float mx = fmaxf(fmaxf(v.x, v.y), fmaxf(v.z, v.w));
    red[t] = mx;
    __syncthreads();
    for (int s = 512; s > 0; s >>= 1) {
        if (t < s) red[t] = fmaxf(red[t], red[t + s]);
        __syncthreads();
    }
    float M = red[0];
    __syncthreads();
    float e0 = expf(v.x - M), e1 = expf(v.y - M), e2 = expf(v.z - M), e3 = expf(v.w - M);
    red[t] = e0 + e1 + e2 + e3;
    __syncthreads();
    for (int s = 512; s > 0; s >>= 1) {
        if (t < s) red[t] += red[t + s];
        __syncthreads();
    }
    float inv = 1.0f / red[0];
    *(float4*)&alpha[b * 4096 + t * 4] = make_float4(e0 * inv, e1 * inv, e2 * inv, e3 * inv);
}

// ---------------------------------------------------------------------------
// Pool: pooled[b,c] = sum_n alpha[b,n]*g3[b,n,c]; thread: 4 cols (ushort4)
// ---------------------------------------------------------------------------
__global__ __launch_bounds__(256) void pool_kernel(
    const ushort* __restrict__ g3, const float* __restrict__ alpha,
    float* __restrict__ pooled) {
    int c4 = threadIdx.x * 4;
    int b = blockIdx.y;
    int n0 = blockIdx.z * 128;
    const ushort* base = g3 + ((size_t)b * 4096 + n0) * 1024 + c4;
    const float* al = alpha + b * 4096 + n0;
    float a0 = 0.f, a1 = 0.f, a2 = 0.f, a3 = 0.f;
#pragma unroll 4
    for (int n = 0; n < 128; ++n) {
        float w = al[n];
        ushort4 gv = *(const ushort4*)&base[(size_t)n * 1024];
        a0 += w * b2f(gv.x); a1 += w * b2f(gv.y);
        a2 += w * b2f(gv.z); a3 += w * b2f(gv.w);
    }
    float* pd = &pooled[b * 1024 + c4];
    atomicAdd(pd + 0, a0); atomicAdd(pd + 1, a1);
    atomicAdd(pd + 2, a2); atomicAdd(pd + 3, a3);
}

// ---------------------------------------------------------------------------
// Heads: wave-per-output, transposed fp32 weights (contiguous float4 reads)
// ---------------------------------------------------------------------------
__global__ __launch_bounds__(256) void head1_kernel(
    const float* __restrict__ pooled, const float* __restrict__ wt1,
    const float* __restrict__ g, const float* __restrict__ bb,
    const float* __restrict__ m, const float* __restrict__ v,
    float* __restrict__ h1) {
    int wv = (blockIdx.x * 256 + threadIdx.x) >> 6;
    int ln = threadIdx.x & 63;
    int b = wv >> 9, c = wv & 511;
    const float4* wp = (const float4*)&wt1[(size_t)c * 1024];
    const float4* pp = (const float4*)&pooled[b * 1024];
    float s = 0.f;
#pragma unroll
    for (int j = 0; j < 4; ++j) {
        float4 w4 = wp[ln * 4 + j], p4 = pp[ln * 4 + j];
        s += w4.x * p4.x + w4.y * p4.y + w4.z * p4.z + w4.w * p4.w;
    }
#pragma unroll
    for (int o = 32; o > 0; o >>= 1) s += __shfl_xor(s, o);
    if (ln == 0) {
        float sc = g[c] * rsqrtf(v[c] + 1e-5f);
        float sh = bb[c] - m[c] * sc;
        h1[b * 512 + c] = fmaxf(s * sc + sh, 0.0f);
    }
}

__global__ __launch_bounds__(256) void head2_kernel(
    const float* __restrict__ h1, const float* __restrict__ wt2,
    const float* __restrict__ g, const float* __restrict__ bb,
    const float* __restrict__ m, const float* __restrict__ v,
    float* __restrict__ h2) {
    int wv = (blockIdx.x * 256 + threadIdx.x) >> 6;
    int ln = threadIdx.x & 63;
    int b = wv >> 8, c = wv & 255;
    const float4* wp = (const float4*)&wt2[(size_t)c * 512];
    const float4* pp = (const float4*)&h1[b * 512];
    float s = 0.f;
#pragma unroll
    for (int j = 0; j < 2; ++j) {
        float4 w4 = wp[ln * 2 + j], p4 = pp[ln * 2 + j];
        s += w4.x * p4.x + w4.y * p4.y + w4.z * p4.z + w4.w * p4.w;
    }
#pragma unroll
    for (int o = 32; o > 0; o >>= 1) s += __shfl_xor(s, o);
    if (ln == 0) {
        float sc = g[c] * rsqrtf(v[c] + 1e-5f);
        float sh = bb[c] - m[c] * sc;
        h2[b * 256 + c] = fmaxf(s * sc + sh, 0.0f);
    }
}

__global__ __launch_bounds__(64) void head3_kernel(
    const float* __restrict__ h2, const float* __restrict__ pw,
    const float* __restrict__ pb, float* __restrict__ out) {
    int b = blockIdx.x, ln = threadIdx.x;
    float4 hv = *(const float4*)&h2[b * 256 + ln * 4];
    float4 wv = *(const float4*)&pw[ln * 4];
    float sum = hv.x * wv.x + hv.y * wv.y + hv.z * wv.z + hv.w * wv.w;
#pragma unroll
    for (int o = 32; o > 0; o >>= 1) sum += __shfl_xor(sum, o);
    if (ln == 0) out[b] = sum + pb[0];
}

// ---------------------------------------------------------------------------
extern "C" void kernel_launch(void* const* d_in, const int* in_sizes, int n_in,
                              void* d_out, int out_size, void* d_ws, size_t ws_size,
                              hipStream_t stream) {
    (void)in_sizes; (void)n_in; (void)out_size; (void)ws_size;
    const float* xyz = (const float*)d_in[0];
    const float* pts = (const float*)d_in[1];
    const float* sa1_w1 = (const float*)d_in[2];
    const float* bn1g = (const float*)d_in[3];
    const float* bn1b = (const float*)d_in[4];
    const float* bn1m = (const float*)d_in[5];
    const float* bn1v = (const float*)d_in[6];
    const float* sa1_w2 = (const float*)d_in[7];
    const float* bn2g = (const float*)d_in[8];
    const float* bn2b = (const float*)d_in[9];
    const float* bn2m = (const float*)d_in[10];
    const float* bn2v = (const float*)d_in[11];
    const float* sa1_w3 = (const float*)d_in[12];
    const float* bn3g = (const float*)d_in[13];
    const float* bn3b = (const float*)d_in[14];
    const float* bn3m = (const float*)d_in[15];
    const float* bn3v = (const float*)d_in[16];
    const float* att1w = (const float*)d_in[17];
    const float* att1b = (const float*)d_in[18];
    const float* sa3_w1 = (const float*)d_in[19];
    const float* s1g = (const float*)d_in[20];
    const float* s1b = (const float*)d_in[21];
    const float* s1m = (const float*)d_in[22];
    const float* s1v = (const float*)d_in[23];
    const float* sa3_w2 = (const float*)d_in[24];
    const float* s2g = (const float*)d_in[25];
    const float* s2b = (const float*)d_in[26];
    const float* s2m = (const float*)d_in[27];
    const float* s2v = (const float*)d_in[28];
    const float* sa3_w3 = (const float*)d_in[29];
    const float* s3g = (const float*)d_in[30];
    const float* s3b = (const float*)d_in[31];
    const float* s3m = (const float*)d_in[32];
    const float* s3v = (const float*)d_in[33];
    const float* att3w = (const float*)d_in[34];
    const float* fc1w = (const float*)d_in[35];
    const float* h1g = (const float*)d_in[36];
    const float* h1b = (const float*)d_in[37];
    const float* h1m = (const float*)d_in[38];
    const float* h1v = (const float*)d_in[39];
    const float* fc2w = (const float*)d_in[40];
    const float* h2g = (const float*)d_in[41];
    const float* h2b = (const float*)d_in[42];
    const float* h2m = (const float*)d_in[43];
    const float* h2v = (const float*)d_in[44];
    const float* predw = (const float*)d_in[45];
    const float* predb = (const float*)d_in[46];
    float* out = (float*)d_out;

    // ---- workspace ----
    char* wsb = (char*)d_ws;
    size_t off = 0;
    auto alloc = [&](size_t bytes) -> void* {
        off = (off + 255) & ~(size_t)255;
        void* p = wsb + off;
        off += bytes;
        return p;
    };
    ushort* Wt2 = (ushort*)alloc(128 * 64 * 2);
    ushort* Wt3 = (ushort*)alloc(256 * 128 * 2);
    ushort* WtS1 = (ushort*)alloc(256 * 256 * 2);
    ushort* WtS2 = (ushort*)alloc(512 * 256 * 2);
    ushort* WtS3 = (ushort*)alloc(1024 * 512 * 2);
    float* wt1 = (float*)alloc(512 * 1024 * 4);
    float* wt2 = (float*)alloc(256 * 512 * 4);
    float* wxyz = (float*)alloc(768 * 4);
    float* sc1 = (float*)alloc(64 * 4);   float* sh1 = (float*)alloc(64 * 4);
    float* sc2 = (float*)alloc(128 * 4);  float* sh2 = (float*)alloc(128 * 4);
    float* sc3 = (float*)alloc(256 * 4);  float* sh3 = (float*)alloc(256 * 4);
    float* scS1 = (float*)alloc(256 * 4); float* shS1 = (float*)alloc(256 * 4);
    float* scS2 = (float*)alloc(512 * 4); float* shS2 = (float*)alloc(512 * 4);
    float* scS3 = (float*)alloc(1024 * 4); float* shS3 = (float*)alloc(1024 * 4);
    float* logitsP = (float*)alloc((size_t)16 * M_ROWS * 4);
    float* alpha = (float*)alloc((size_t)M_ROWS * 4);
    float* pooled = (float*)alloc(16 * 1024 * 4);
    float* h1buf = (float*)alloc(16 * 512 * 4);
    float* h2buf = (float*)alloc(16 * 256 * 4);

    // big region, overlaid by live range. G stride 256 (32 MB).
    off = (off + MB - 1) & ~(MB - 1);
    char* bigA = wsb + off;            // 128 MB
    char* bigB = bigA + 128 * MB;      // 64 MB
    ushort* G  = (ushort*)(bigA);             // 32 MB  [fused, S1)
    ushort* g1 = (ushort*)(bigA + 32 * MB);   // 32 MB  [S1, S2)
    ushort* g3 = (ushort*)(bigA);             // 128 MB [S3, pool)
    ushort* g2 = (ushort*)(bigB);             // 64 MB  [S2, S3)

    // ---- prep2 ----
    Prep2Args pa;
    const float* srcs[7] = {sa1_w2, sa1_w3, sa3_w1, sa3_w2, sa3_w3, fc1w, fc2w};
    void* dsts[7] = {Wt2, Wt3, WtS1, WtS2, WtS3, wt1, wt2};
    int Ks[7] = {64, 128, 256, 256, 512, 1024, 512};
    int Ns[7] = {128, 256, 256, 512, 1024, 512, 256};
    int Kps[7] = {64, 128, 256, 256, 512, 1024, 512};
    int isBF[7] = {1, 1, 1, 1, 1, 0, 0};
    int maxTiles = 0;
    for (int i = 0; i < 7; ++i) {
        pa.src[i] = srcs[i]; pa.dst[i] = dsts[i];
        pa.K[i] = Ks[i]; pa.N[i] = Ns[i]; pa.Kp[i] = Kps[i];
        pa.isBF[i] = isBF[i];
        pa.tiles[i] = (Kps[i] >> 5) * (Ns[i] >> 5);
        if (pa.tiles[i] > maxTiles) maxTiles = pa.tiles[i];
    }
    const float* gs[6] = {bn1g, bn2g, bn3g, s1g, s2g, s3g};
    const float* bbs[6] = {bn1b, bn2b, bn3b, s1b, s2b, s3b};
    const float* mms[6] = {bn1m, bn2m, bn3m, s1m, s2m, s3m};
    const float* vvs[6] = {bn1v, bn2v, bn3v, s1v, s2v, s3v};
    float* scs[6] = {sc1, sc2, sc3, scS1, scS2, scS3};
    float* shs[6] = {sh1, sh2, sh3, shS1, shS2, shS3};
    int Cs6[6] = {64, 128, 256, 256, 512, 1024};
    for (int i = 0; i < 6; ++i) {
        pa.g[i] = gs[i]; pa.bb[i] = bbs[i]; pa.mm[i] = mms[i]; pa.vv[i] = vvs[i];
        pa.sc[i] = scs[i]; pa.sh[i] = shs[i]; pa.C[i] = Cs6[i];
    }
    pa.xyzsrc = sa3_w1;
    pa.wxyz = wxyz;
    pa.pooled = pooled;
    prep2_kernel<<<dim3(maxTiles, 8), 256, 0, stream>>>(pa);

    // ---- SA1 fused front: xyz/pts -> G [M,256] ----
    sa1_fused<<<M_ROWS / 128, 512, 0, stream>>>(
        xyz, pts, sa1_w1, sc1, sh1, Wt2, sc2, sh2, Wt3, sc3, sh3,
        att1w, att1b, G);
    // ---- SA3 ----
    gemm_s1<<<512 * 2, 256, 0, stream>>>(G, WtS1, scS1, shS1, g1, 256, 256, 2, 256, xyz, wxyz);
    gemm_bn_relu<<<512 * 4, 256, 0, stream>>>(g1, WtS2, scS2, shS2, g2, 512, 256, 4, 512, nullptr, nullptr);
    gemm_bn_relu<<<512 * 8, 256, 0, stream>>>(g2, WtS3, scS3, shS3, g3, 1024, 512, 8, 1024, att3w, logitsP);
    // ---- attention pooling ----
    softmax_kernel<<<16, 1024, 0, stream>>>(logitsP, alpha);
    pool_kernel<<<dim3(1, 16, 32), 256, 0, stream>>>(g3, alpha, pooled);
    // ---- head ----
    head1_kernel<<<2048, 256, 0, stream>>>(pooled, wt1, h1g, h1b, h1m, h1v, h1buf);
    head2_kernel<<<1024, 256, 0, stream>>>(h1buf, wt2, h2g, h2b, h2m, h2v, h2buf);
    head3_kernel<<<16, 64, 0, stream>>>(h2buf, predw, predb, out);
}